// Round 2
// baseline (367.639 us; speedup 1.0000x reference)
//
#include <hip/hip_runtime.h>
#include <math.h>

// Problem constants (from reference setup_inputs)
#define BB 16
#define FF 256
#define TT 8192
#define KK 204   // int(256 * (1 - 0.2)) = 204 kept per row

// Kernel 1: compute the exact 0/1 mask, 16 blocks x 256 threads (~3 us).
// Replicates: sig = sigmoid(w)+noise*0.05; keep iff (#strictly greater) < K
// (identical to x2 >= kth-largest, tie-inclusive); straight-through binary
// collapses exactly to hard = (clip((wta+1)*0.5,0,1) > 0.5).
__global__ void mask_kernel(const float* __restrict__ w,
                            const float* __restrict__ noise,
                            float* __restrict__ mask) {
    __shared__ float vals[FF];
    const int b = blockIdx.x;
    const int f = threadIdx.x;
    float v = 1.0f / (1.0f + expf(-w[f])) + noise[b * FF + f] * 0.05f;
    vals[f] = v;
    __syncthreads();
    int cnt = 0;
#pragma unroll 8
    for (int j = 0; j < FF; ++j) cnt += (vals[j] > v) ? 1 : 0;
    float wta = (cnt < KK) ? v : 0.0f;
    float p = fminf(fmaxf((wta + 1.0f) * 0.5f, 0.0f), 1.0f);
    mask[b * FF + f] = (p > 0.5f) ? 1.0f : 0.0f;
}

// Kernel 2: fused streaming writer, block-partitioned (no per-iter branches).
//   blocks [0,4096):    masked_x  — block = one (b,f) row of 8192 floats.
//                       mask scalar loaded ONCE, 8 unrolled float4 copy-scales.
//   blocks [4096,6144): binary_mask — 128 blocks per b, 64 t-rows per block.
//                       mask float4 hoisted to register, pure wave-coalesced
//                       1 KB row stores (16 per thread).
__global__ void __launch_bounds__(256) apply_kernel(const float4* __restrict__ x4,
                                                    const float* __restrict__ mask,
                                                    float4* __restrict__ out4) {
    const int bid = blockIdx.x;
    if (bid < BB * FF) {
        // masked_x: row bid = b*256+f, 2048 float4 per row
        const float m = mask[bid];
        const float4* __restrict__ src = x4 + ((size_t)bid << 11);
        float4* __restrict__ dst = out4 + ((size_t)bid << 11);
        int t = threadIdx.x;
#pragma unroll
        for (int u = 0; u < 8; ++u, t += 256) {
            float4 v = src[t];
            v.x *= m; v.y *= m; v.z *= m; v.w *= m;
            dst[t] = v;
        }
    } else {
        // binary_mask region starts at float4 index B*F*T/4 = 8388608
        const int q = bid - BB * FF;         // 0..2047
        const int b = q >> 7;                // 128 blocks per b
        const int tchunk = q & 127;          // each covers 64 t-rows
        const int lane = threadIdx.x & 63;
        const int wid = threadIdx.x >> 6;    // 4 waves
        const float4* __restrict__ m4 = (const float4*)mask;
        const float4 mv = m4[(b << 6) | lane];
        float4* __restrict__ dst =
            out4 + (size_t)(BB * FF * TT / 4) + ((size_t)(b * TT + (tchunk << 6)) << 6);
#pragma unroll
        for (int t = 0; t < 64; t += 4) {
            dst[((size_t)(t + wid) << 6) | lane] = mv;  // wave writes 1 KB row
        }
    }
}

extern "C" void kernel_launch(void* const* d_in, const int* in_sizes, int n_in,
                              void* d_out, int out_size, void* d_ws, size_t ws_size,
                              hipStream_t stream) {
    const float* x     = (const float*)d_in[0];   // (16,1,256,8192)
    const float* w     = (const float*)d_in[1];   // (1,1,1,256)
    const float* noise = (const float*)d_in[2];   // (16,1,1,256)
    float* out  = (float*)d_out;
    float* mask = (float*)d_ws;                   // 16 KB scratch

    (void)out_size; (void)ws_size; (void)n_in; (void)in_sizes;

    mask_kernel<<<BB, FF, 0, stream>>>(w, noise, mask);
    apply_kernel<<<BB * FF + 2048, 256, 0, stream>>>((const float4*)x, mask, (float4*)out);
}

// Round 3
// 351.684 us; speedup vs baseline: 1.0454x; 1.0454x over previous
//
#include <hip/hip_runtime.h>
#include <math.h>

// Problem constants (from reference setup_inputs)
#define BB 16
#define FF 256
#define TT 8192
#define KK 204   // int(256 * (1 - 0.2)) = 204 kept per row

typedef float v4 __attribute__((ext_vector_type(4)));

// Fully fused kernel, 6144 blocks x 256 threads.
//   blocks [0,4096):    masked_x  — block = one (b,f) row of 8192 floats.
//                       x prefetched to regs, mask bit via ballot-count,
//                       NT load/store streaming.
//   blocks [4096,6144): binary_mask — 128 blocks per b; block recomputes the
//                       full 256-wide mask row in LDS, then pure NT
//                       wave-coalesced 1 KB row stores.
// Mask semantics (exact): v = sigmoid(w[f]) + noise[b,f]*0.05;
//   keep iff (#{j : v_j > v_f} < K)  [== x2 >= kth-largest, tie-inclusive];
//   straight-through binary == hard == (clip((wta+1)*0.5,0,1) > 0.5)
//   == (kept && v_f > 0).
__global__ void __launch_bounds__(256) fused_kernel(const v4* __restrict__ x4,
                                                    const float* __restrict__ w,
                                                    const float* __restrict__ noise,
                                                    v4* __restrict__ out4) {
    __shared__ float vals[FF];
    __shared__ float mrow[FF];
    __shared__ int wcnt[4];

    const int bid = blockIdx.x;
    const int tid = threadIdx.x;
    const bool is_mx = (bid < BB * FF);
    const int b = is_mx ? (bid >> 8) : ((bid - BB * FF) >> 7);

    // per-(b,tid) sparsify input value
    const float v = 1.0f / (1.0f + expf(-w[tid])) + noise[b * FF + tid] * 0.05f;

    if (is_mx) {
        // ---- masked_x: row bid = b*256+f, 2048 float4 ----
        const v4* __restrict__ src = x4 + ((size_t)bid << 11);
        v4* __restrict__ dst = out4 + ((size_t)bid << 11);

        // prefetch x while the mask bit is being derived
        v4 xv[8];
#pragma unroll
        for (int u = 0; u < 8; ++u)
            xv[u] = __builtin_nontemporal_load(&src[tid + (u << 8)]);

        vals[tid] = v;
        __syncthreads();
        const float vf = vals[bid & 255];
        unsigned long long ball = __ballot(v > vf);
        if ((tid & 63) == 0) wcnt[tid >> 6] = __popcll(ball);
        __syncthreads();
        const int cnt = wcnt[0] + wcnt[1] + wcnt[2] + wcnt[3];
        const float m = (cnt < KK && vf > 0.0f) ? 1.0f : 0.0f;

#pragma unroll
        for (int u = 0; u < 8; ++u) {
            v4 o = xv[u] * m;
            __builtin_nontemporal_store(o, &dst[tid + (u << 8)]);
        }
    } else {
        // ---- binary_mask: (B,1,T,F); 128 blocks per b, 64 t-rows each ----
        vals[tid] = v;
        __syncthreads();
        int cnt = 0;
#pragma unroll 8
        for (int j = 0; j < FF; ++j) cnt += (vals[j] > v) ? 1 : 0;
        mrow[tid] = (cnt < KK && v > 0.0f) ? 1.0f : 0.0f;
        __syncthreads();

        const int q = bid - BB * FF;       // 0..2047
        const int tchunk = q & 127;        // 64 t-rows per block
        const int lane = tid & 63;
        const int wid = tid >> 6;          // 4 waves
        const v4 mv = ((const v4*)mrow)[lane];
        v4* __restrict__ dst = out4 + (size_t)(BB * FF * TT / 4)
                             + ((size_t)(b * TT + (tchunk << 6)) << 6);
#pragma unroll
        for (int t = 0; t < 64; t += 4)
            __builtin_nontemporal_store(mv, &dst[((size_t)(t + wid) << 6) | lane]);
    }
}

extern "C" void kernel_launch(void* const* d_in, const int* in_sizes, int n_in,
                              void* d_out, int out_size, void* d_ws, size_t ws_size,
                              hipStream_t stream) {
    const float* x     = (const float*)d_in[0];   // (16,1,256,8192)
    const float* w     = (const float*)d_in[1];   // (1,1,1,256)
    const float* noise = (const float*)d_in[2];   // (16,1,1,256)

    (void)out_size; (void)ws_size; (void)d_ws; (void)n_in; (void)in_sizes;

    fused_kernel<<<BB * FF + 2048, 256, 0, stream>>>(
        (const v4*)x, w, noise, (v4*)d_out);
}

// Round 4
// 348.374 us; speedup vs baseline: 1.0553x; 1.0095x over previous
//
#include <hip/hip_runtime.h>
#include <math.h>

// Problem constants (from reference setup_inputs)
#define BB 16
#define FF 256
#define TT 8192
#define KK 204   // int(256 * (1 - 0.2)) = 204 kept per row

typedef float v4 __attribute__((ext_vector_type(4)));

// Fully fused kernel, 6144 blocks x 256 threads.
//   blocks [0,4096):    masked_x  — block = one (b,f) row of 8192 floats.
//                       Mask bit computed FIRST (ballot + LDS combine);
//                       kept rows: NT 8x float4 copy; dropped rows: store
//                       zeros, NO x read (saves 20.3% of fetch traffic).
//   blocks [4096,6144): binary_mask — 128 blocks per b; block recomputes the
//                       full 256-wide mask row in LDS, then pure NT
//                       wave-coalesced 1 KB row stores.
// Mask semantics (exact): v = sigmoid(w[f]) + noise[b,f]*0.05;
//   keep iff (#{j : v_j > v_f} < K)  [== x2 >= kth-largest, tie-inclusive];
//   straight-through binary == hard == (clip((wta+1)*0.5,0,1) > 0.5)
//   == (kept && v_f > 0).
__global__ void __launch_bounds__(256) fused_kernel(const v4* __restrict__ x4,
                                                    const float* __restrict__ w,
                                                    const float* __restrict__ noise,
                                                    v4* __restrict__ out4) {
    __shared__ float vals[FF];
    __shared__ float mrow[FF];
    __shared__ int wcnt[4];

    const int bid = blockIdx.x;
    const int tid = threadIdx.x;
    const bool is_mx = (bid < BB * FF);
    const int b = is_mx ? (bid >> 8) : ((bid - BB * FF) >> 7);

    // per-(b,tid) sparsify input value
    const float v = 1.0f / (1.0f + expf(-w[tid])) + noise[b * FF + tid] * 0.05f;

    if (is_mx) {
        // ---- masked_x: row bid = b*256+f, 2048 float4 ----
        vals[tid] = v;
        __syncthreads();
        const float vf = vals[bid & 255];
        unsigned long long ball = __ballot(v > vf);
        if ((tid & 63) == 0) wcnt[tid >> 6] = __popcll(ball);
        __syncthreads();
        const int cnt = wcnt[0] + wcnt[1] + wcnt[2] + wcnt[3];
        const bool keep = (cnt < KK) && (vf > 0.0f);

        const v4* __restrict__ src = x4 + ((size_t)bid << 11);
        v4* __restrict__ dst = out4 + ((size_t)bid << 11);

        if (keep) {          // block-uniform branch
            v4 xv[8];
#pragma unroll
            for (int u = 0; u < 8; ++u)
                xv[u] = __builtin_nontemporal_load(&src[tid + (u << 8)]);
#pragma unroll
            for (int u = 0; u < 8; ++u)
                __builtin_nontemporal_store(xv[u], &dst[tid + (u << 8)]);
        } else {
            const v4 z = {0.0f, 0.0f, 0.0f, 0.0f};
#pragma unroll
            for (int u = 0; u < 8; ++u)
                __builtin_nontemporal_store(z, &dst[tid + (u << 8)]);
        }
    } else {
        // ---- binary_mask: (B,1,T,F); 128 blocks per b, 64 t-rows each ----
        vals[tid] = v;
        __syncthreads();
        int cnt = 0;
#pragma unroll 8
        for (int j = 0; j < FF; ++j) cnt += (vals[j] > v) ? 1 : 0;
        mrow[tid] = (cnt < KK && v > 0.0f) ? 1.0f : 0.0f;
        __syncthreads();

        const int q = bid - BB * FF;       // 0..2047
        const int tchunk = q & 127;        // 64 t-rows per block
        const int lane = tid & 63;
        const int wid = tid >> 6;          // 4 waves
        const v4 mv = ((const v4*)mrow)[lane];
        v4* __restrict__ dst = out4 + (size_t)(BB * FF * TT / 4)
                             + ((size_t)(b * TT + (tchunk << 6)) << 6);
#pragma unroll
        for (int t = 0; t < 64; t += 4)
            __builtin_nontemporal_store(mv, &dst[((size_t)(t + wid) << 6) | lane]);
    }
}

extern "C" void kernel_launch(void* const* d_in, const int* in_sizes, int n_in,
                              void* d_out, int out_size, void* d_ws, size_t ws_size,
                              hipStream_t stream) {
    const float* x     = (const float*)d_in[0];   // (16,1,256,8192)
    const float* w     = (const float*)d_in[1];   // (1,1,1,256)
    const float* noise = (const float*)d_in[2];   // (16,1,1,256)

    (void)out_size; (void)ws_size; (void)d_ws; (void)n_in; (void)in_sizes;

    fused_kernel<<<BB * FF + 2048, 256, 0, stream>>>(
        (const v4*)x, w, noise, (v4*)d_out);
}